// Round 9
// baseline (139.623 us; speedup 1.0000x reference)
//
#include <hip/hip_runtime.h>
#include <hip/hip_bf16.h>

// Problem constants
#define BB 16
#define SS 384
#define HH 1024
#define NH 16
#define HD 64
#define MM (BB*SS)        // 6144
#define KK HH             // 1024
#define N3 (3*HH)         // 3072

typedef float f32x4 __attribute__((ext_vector_type(4)));
typedef __bf16 bf16x8 __attribute__((ext_vector_type(8)));
typedef unsigned short us8 __attribute__((ext_vector_type(8)));
typedef unsigned short us4 __attribute__((ext_vector_type(4)));
typedef unsigned int u32x4 __attribute__((ext_vector_type(4)));

__device__ __forceinline__ void gload_lds16(const void* g, void* l) {
    __builtin_amdgcn_global_load_lds(
        (const __attribute__((address_space(1))) void*)g,
        (__attribute__((address_space(3))) void*)l, 16, 0, 0);
}

__device__ __forceinline__ unsigned short f2b(float f) {
    __bf16 h = (__bf16)f;
    return __builtin_bit_cast(unsigned short, h);
}

// ---------------- kernel 0a: activation f32 -> bf16 ----------------
__global__ __launch_bounds__(256) void cvt_x(const float4* __restrict__ in,
                                             us4* __restrict__ out, int n4) {
    int i = blockIdx.x * 256 + threadIdx.x;
    if (i < n4) {
        float4 v = in[i];
        us4 o;
        o.x = f2b(v.x); o.y = f2b(v.y); o.z = f2b(v.z); o.w = f2b(v.w);
        out[i] = o;
    }
}

// ---------------- kernel 0b: W [K][N3] f32 -> WT [N3][K] bf16 ----------------
__global__ __launch_bounds__(256) void cvt_w(const float* __restrict__ Wf,
                                             __bf16* __restrict__ WT) {
    __shared__ float tile[32][33];
    const int n0 = blockIdx.x * 32, k0 = blockIdx.y * 32;
    const int t = threadIdx.x;
    const int tj = t & 31, ti = t >> 5;   // ti 0..7
#pragma unroll
    for (int p = 0; p < 4; ++p) {
        int i = p * 8 + ti;
        tile[i][tj] = Wf[(size_t)(k0 + i) * N3 + n0 + tj];
    }
    __syncthreads();
#pragma unroll
    for (int p = 0; p < 4; ++p) {
        int jj = p * 8 + ti;
        WT[(size_t)(n0 + jj) * KK + k0 + tj] = (__bf16)tile[tj][jj];
    }
}

// ---------------- kernel 1: QKV GEMM (R3 m97 structure — proven best) -------
__global__ __launch_bounds__(256) void qkv_gemm(const __bf16* __restrict__ Xb,
                                                const __bf16* __restrict__ WT,
                                                const float* __restrict__ bias,
                                                __bf16* __restrict__ QKb,
                                                __bf16* __restrict__ VTg) {
    __shared__ __bf16 As[128 * 32];
    __shared__ __bf16 Bs[128 * 32];
    const int t = threadIdx.x;
    const int w = t >> 6, lane = t & 63;
    const int wr = w >> 1, wc = w & 1;
    const int l15 = lane & 15, lg = lane >> 4;
    const int m0 = blockIdx.y * 128, n0 = blockIdx.x * 128;

    f32x4 acc[4][4] = {};

    for (int k0 = 0; k0 < KK; k0 += 32) {
#pragma unroll
        for (int i = 0; i < 2; ++i) {
            int slab = w * 2 + i;
            int row = slab * 16 + (lane >> 2);
            int ck = lane & 3;
            gload_lds16(Xb + (size_t)(m0 + row) * KK + k0 + ck * 8, &As[slab * 512]);
            gload_lds16(WT + (size_t)(n0 + row) * KK + k0 + ck * 8, &Bs[slab * 512]);
        }
        __syncthreads();

        bf16x8 a[4];
#pragma unroll
        for (int i = 0; i < 4; ++i) {
            int row = wr * 64 + i * 16 + l15;
            a[i] = *(const bf16x8*)&As[row * 32 + lg * 8];
        }
#pragma unroll
        for (int j = 0; j < 4; ++j) {
            int row = wc * 64 + j * 16 + l15;
            bf16x8 bv = *(const bf16x8*)&Bs[row * 32 + lg * 8];
#pragma unroll
            for (int i = 0; i < 4; ++i)
                acc[i][j] = __builtin_amdgcn_mfma_f32_16x16x32_bf16(a[i], bv, acc[i][j], 0, 0, 0);
        }
        __syncthreads();
    }

#pragma unroll
    for (int j = 0; j < 4; ++j) {
        int c = n0 + wc * 64 + j * 16 + l15;
        float bv = bias[c];
#pragma unroll
        for (int i = 0; i < 4; ++i) {
#pragma unroll
            for (int r = 0; r < 4; ++r) {
                int rr = m0 + wr * 64 + i * 16 + lg * 4 + r;
                float v = acc[i][j][r] + bv;
                if (c < 2048) {
                    QKb[(size_t)rr * 2048 + c] = (__bf16)v;
                } else {
                    int d = c & 63;
                    int hh = (c - 2048) >> 6;
                    int bb = rr / SS;
                    int s = rr - bb * SS;
                    VTg[((size_t)(bb * NH + hh) * HD + d) * SS + s] = (__bf16)v;
                }
            }
        }
    }
}

// ---------------- kernel 2: attention — K-only LDS, V direct + prefetch -----
// 512 blocks = (head, q-half), 256 threads (4 waves). LDS = K + mask only
// (50.7 KB) -> 2 independent blocks/CU: block B's staging overlaps block A's
// compute. Swapped QK^T (validated R8): lane (l15,lg) holds S[q=l15][k].
// V^T B-frags read DIRECT from global (pattern validated R6) with a rolling
// 4-group prefetch whose latency hides under softmax / earlier PV MFMAs.
#define AKLOFF 0                    // K   [384][64] bf16, swizzled  (49152)
#define AMKOFF 49152                // mask[384] f32                 (1536)
#define ASMEM  50688

#define LOADV(VR, ST) do {                                                    \
    _Pragma("unroll")                                                         \
    for (int j = 0; j < 4; ++j)                                               \
        VR[j] = *(const bf16x8*)&Vh[(size_t)(j * 16 + l15) * SS + (ST) * 32 + lg * 8]; \
} while (0)

#define PVST(VR, ST, NST) do {                                                \
    bf16x8 pa = __builtin_bit_cast(bf16x8, paw[ST]);                          \
    _Pragma("unroll")                                                         \
    for (int j = 0; j < 4; ++j)                                               \
        o[j] = __builtin_amdgcn_mfma_f32_16x16x32_bf16(pa, VR[j], o[j], 0, 0, 0); \
    if ((NST) < 12) LOADV(VR, NST);                                           \
} while (0)

__global__ __launch_bounds__(256) void attn(const __bf16* __restrict__ QKb,
                                            const __bf16* __restrict__ VTg,
                                            const float* __restrict__ maskg,
                                            float* __restrict__ out) {
    extern __shared__ char smem[];
    const int bid = blockIdx.x;
    const int head = bid >> 1, qh = bid & 1;
    const int b = head >> 4, h = head & 15;
    const int t = threadIdx.x;
    const int wv = t >> 6, lane = t & 63;
    const int l15 = lane & 15, lg = lane >> 4;
    const __bf16* Vh = VTg + (size_t)head * HD * SS;

    // ---- Q fragments for this wave's 3 q-chunks, hoisted (latency hides
    // under the K staging loop) ----
    bf16x8 bq[3][2];
#pragma unroll
    for (int c = 0; c < 3; ++c) {
        const size_t qr = (size_t)(b * SS + qh * 192 + (wv + 4 * c) * 16 + l15) * 2048 + h * 64;
#pragma unroll
        for (int st = 0; st < 2; ++st)
            bq[c][st] = *(const bf16x8*)&QKb[qr + st * 32 + lg * 8];
    }

    // ---- stage K [s][d] rows 128B, XOR swizzle (row&7)<<4 ----
    for (int it = 0; it < 12; ++it) {
        int slot = it * 256 + t;
        int row = slot >> 3, ck = slot & 7;
        us8 v = *(const us8*)&QKb[(size_t)(b * SS + row) * 2048 + 1024 + h * 64 + ck * 8];
        int byte = (row * 128 + ck * 16) ^ ((row & 7) << 4);
        *(us8*)(smem + AKLOFF + byte) = v;
    }
    for (int s = t; s < SS; s += 256)
        ((float*)(smem + AMKOFF))[s] = maskg[b * SS + s];
    __syncthreads();   // ONLY barrier — LDS read-only afterwards

    const int srcA = l15 + 32 * (lg & 1);
    const int srcB = srcA + 16;
    const float* mrow = (const float*)(smem + AMKOFF);

#pragma unroll
    for (int c = 0; c < 3; ++c) {
        const int q0c = qh * 192 + (wv + 4 * c) * 16;

        // ---- QK^T (swapped): acc[f] rows k=16f+4lg+r, col q=l15 ----
        f32x4 acc[24];
#pragma unroll
        for (int f = 0; f < 24; ++f) acc[f] = f32x4{0.f, 0.f, 0.f, 0.f};
        __builtin_amdgcn_s_setprio(1);
#pragma unroll
        for (int f = 0; f < 24; ++f) {
            int row = f * 16 + l15;
#pragma unroll
            for (int st = 0; st < 2; ++st) {
                bf16x8 kb = *(const bf16x8*)(smem + AKLOFF +
                             ((row * 128 + st * 64 + lg * 16) ^ ((row & 7) << 4)));
                acc[f] = __builtin_amdgcn_mfma_f32_16x16x32_bf16(kb, bq[c][st], acc[f], 0, 0, 0);
            }
        }
        __builtin_amdgcn_s_setprio(0);

        // ---- issue V prefetch groups 0..3 (latency hides under softmax) ----
        bf16x8 va[4], vb_[4], vc[4], vd[4];
        LOADV(va, 0); LOADV(vb_, 1); LOADV(vc, 2); LOADV(vd, 3);

        // ---- scale + mask (mask varies along k=16f+4lg+r) + row max ----
        float mx = -1e30f;
#pragma unroll
        for (int f = 0; f < 24; ++f) {
            float4 mk = *(const float4*)(mrow + f * 16 + 4 * lg);
            acc[f][0] = acc[f][0] * 0.125f + mk.x;
            acc[f][1] = acc[f][1] * 0.125f + mk.y;
            acc[f][2] = acc[f][2] * 0.125f + mk.z;
            acc[f][3] = acc[f][3] * 0.125f + mk.w;
            mx = fmaxf(mx, fmaxf(fmaxf(acc[f][0], acc[f][1]), fmaxf(acc[f][2], acc[f][3])));
        }
        mx = fmaxf(mx, __shfl_xor(mx, 16, 64));
        mx = fmaxf(mx, __shfl_xor(mx, 32, 64));

        // ---- exp + row sum ----
        float sm = 0.f;
#pragma unroll
        for (int f = 0; f < 24; ++f) {
#pragma unroll
            for (int r = 0; r < 4; ++r) {
                float p = __expf(acc[f][r] - mx);
                acc[f][r] = p;
                sm += p;
            }
        }
        sm += __shfl_xor(sm, 16, 64);
        sm += __shfl_xor(sm, 32, 64);
        const float inv = 1.f / sm;

        // ---- pack P to bf16 pairs (unnormalized, <=1) ----
        unsigned pk0[24], pk1[24];
#pragma unroll
        for (int f = 0; f < 24; ++f) {
            pk0[f] = (unsigned)f2b(acc[f][0]) | ((unsigned)f2b(acc[f][1]) << 16);
            pk1[f] = (unsigned)f2b(acc[f][2]) | ((unsigned)f2b(acc[f][3]) << 16);
        }

        // ---- redistribute to PV A-fragments via shfl (validated R8) ----
        u32x4 paw[12];
#pragma unroll
        for (int f = 0; f < 24; ++f) {
            unsigned a0 = __shfl(pk0[f], srcA, 64);
            unsigned a1 = __shfl(pk1[f], srcA, 64);
            unsigned b0 = __shfl(pk0[f], srcB, 64);
            unsigned b1 = __shfl(pk1[f], srcB, 64);
            if ((lg >> 1) == (f & 1))
                paw[f >> 1] = u32x4{a0, a1, b0, b1};
        }

        // ---- PV: O[16][64]; rolling 4-group V prefetch ----
        f32x4 o[4] = {};
        __builtin_amdgcn_s_setprio(1);
        PVST(va, 0, 4);  PVST(vb_, 1, 5);  PVST(vc, 2, 6);   PVST(vd, 3, 7);
        PVST(va, 4, 8);  PVST(vb_, 5, 9);  PVST(vc, 6, 10);  PVST(vd, 7, 11);
        PVST(va, 8, 12); PVST(vb_, 9, 12); PVST(vc, 10, 12); PVST(vd, 11, 12);
        __builtin_amdgcn_s_setprio(0);

        // ---- normalize (inv redistributed: out row q=4lg+r) + store f32 ----
#pragma unroll
        for (int r = 0; r < 4; ++r) {
            float invr = __shfl(inv, 4 * lg + r, 64);
            int qr = q0c + 4 * lg + r;
#pragma unroll
            for (int j = 0; j < 4; ++j)
                out[(size_t)(b * SS + qr) * HH + h * 64 + j * 16 + l15] =
                    o[j][r] * invr;
        }
    }
}

// ---------------- launch ----------------
extern "C" void kernel_launch(void* const* d_in, const int* in_sizes, int n_in,
                              void* d_out, int out_size, void* d_ws, size_t ws_size,
                              hipStream_t stream) {
    const float* act  = (const float*)d_in[0];
    const float* mask = (const float*)d_in[1];
    const float* wq   = (const float*)d_in[2];
    const float* bias = (const float*)d_in[3];

    char* ws = (char*)d_ws;
    __bf16* Xb  = (__bf16*)(ws);                       // 12,582,912 B
    __bf16* WT  = (__bf16*)(ws + 12582912);            //  6,291,456 B
    __bf16* QKb = (__bf16*)(ws + 18874368);            // 25,165,824 B
    __bf16* VTg = (__bf16*)(ws + 44040192);            // 12,582,912 B (end 56.6MB)

    cvt_x<<<(MM * KK / 4 + 255) / 256, 256, 0, stream>>>((const float4*)act, (us4*)Xb, MM * KK / 4);
    cvt_w<<<dim3(N3 / 32, KK / 32), 256, 0, stream>>>(wq, WT);
    qkv_gemm<<<dim3(N3 / 128, MM / 128), 256, 0, stream>>>(Xb, WT, bias, QKb, VTg);

    (void)hipFuncSetAttribute((const void*)attn, hipFuncAttributeMaxDynamicSharedMemorySize, ASMEM);
    attn<<<BB * NH * 2, 256, ASMEM, stream>>>(QKb, VTg, mask, (float*)d_out);
}